// Round 1
// baseline (199.279 us; speedup 1.0000x reference)
//
#include <hip/hip_runtime.h>
#include <hip/hip_bf16.h>

// ParallelExperts: per-expert LayerNorm -> Linear(1024->4096) -> tanh-GELU
// E=16 experts, 512 tokens each (balanced), fp32 in/out, bf16 MFMA inside.

#define E_EXP 16
#define T_TOK 8192
#define DIN   1024
#define DOUT  4096

typedef __bf16 bf16;
typedef __bf16 bf16x4v __attribute__((ext_vector_type(4)));
typedef __bf16 bf16x8v __attribute__((ext_vector_type(8)));
typedef float  f32x4   __attribute__((ext_vector_type(4)));

typedef __attribute__((address_space(1))) void gvoid;
typedef __attribute__((address_space(3))) void lvoid;

// ---------------- LayerNorm -> bf16 (one block per token) ----------------
__global__ __launch_bounds__(256) void ln_bf16_kernel(
    const float* __restrict__ x, const float* __restrict__ gamma,
    const float* __restrict__ beta, bf16* __restrict__ xn) {
  const int t    = blockIdx.x;
  const int e    = t >> 9;            // 512 tokens per expert
  const int tid  = threadIdx.x;
  const float4 xv = reinterpret_cast<const float4*>(x + (size_t)t * DIN)[tid];
  float s  = xv.x + xv.y + xv.z + xv.w;
  float s2 = xv.x * xv.x + xv.y * xv.y + xv.z * xv.z + xv.w * xv.w;
#pragma unroll
  for (int o = 32; o > 0; o >>= 1) {
    s  += __shfl_xor(s,  o, 64);
    s2 += __shfl_xor(s2, o, 64);
  }
  __shared__ float red[8];
  const int lane = tid & 63, wid = tid >> 6;
  if (lane == 0) { red[wid] = s; red[4 + wid] = s2; }
  __syncthreads();
  s  = red[0] + red[1] + red[2] + red[3];
  s2 = red[4] + red[5] + red[6] + red[7];
  const float mu  = s * (1.0f / DIN);
  const float var = s2 * (1.0f / DIN) - mu * mu;
  const float inv = rsqrtf(var + 1e-5f);
  const float4 g = reinterpret_cast<const float4*>(gamma + (size_t)e * DIN)[tid];
  const float4 b = reinterpret_cast<const float4*>(beta  + (size_t)e * DIN)[tid];
  bf16x4v o;
  o[0] = (bf16)((xv.x - mu) * inv * g.x + b.x);
  o[1] = (bf16)((xv.y - mu) * inv * g.y + b.y);
  o[2] = (bf16)((xv.z - mu) * inv * g.z + b.z);
  o[3] = (bf16)((xv.w - mu) * inv * g.w + b.w);
  *reinterpret_cast<bf16x4v*>(xn + (size_t)t * DIN + tid * 4) = o;
}

// ---------------- grouped GEMM: C = GELU(xn @ W[e] + b[e]) ----------------
// 128x128 tile, BK=32, 4 waves (2x2), 4x4 16x16x32 fragments per wave.
#define BM 128
#define BN 128
#define BK 32
#define KPAD 40   // [n][k] LDS stride in bf16: keeps ds_read_b128 16B-aligned

__global__ __launch_bounds__(256) void grouped_gemm_kernel(
    const bf16* __restrict__ xn, const float* __restrict__ W,
    const float* __restrict__ bias, float* __restrict__ out) {
  __shared__ bf16 Alds[BM * BK];     // [m][32] linear (global_load_lds dest), 8 KB
  __shared__ bf16 Blds[BN * KPAD];   // [n][40] transposed W tile, 10 KB

  const int tid    = threadIdx.x;
  const int lane   = tid & 63;
  const int wid    = tid >> 6;
  const int warp_m = wid >> 1;       // 0..1
  const int warp_n = wid & 1;        // 0..1
  const int ntile  = blockIdx.x;     // 0..31
  const int mtile  = blockIdx.y;     // 0..63
  const int e      = mtile >> 2;     // 4 m-tiles per expert
  const int t0     = mtile * BM;
  const int n0     = ntile * BN;

  f32x4 acc[4][4];
#pragma unroll
  for (int i = 0; i < 4; ++i)
#pragma unroll
    for (int j = 0; j < 4; ++j)
      acc[i][j] = (f32x4){0.f, 0.f, 0.f, 0.f};

  const int br = tid >> 3;           // B staging: k-row 0..31
  const int bq = tid & 7;            // B staging: n-quad group 0..7
  const bf16* agsrc_base = xn + (size_t)t0 * DIN;

  for (int ks = 0; ks < DIN / BK; ++ks) {
    const int k0 = ks * BK;
    if (ks) __syncthreads();   // previous tile's fragment reads must be done

    // --- A: xn tile 128x32 bf16, direct global->LDS (16 B/lane, 2 per wave) ---
#pragma unroll
    for (int c = 0; c < 2; ++c) {
      const int cidx = wid * 2 + c;                 // 16-row chunk index 0..7
      const int row  = cidx * 16 + (lane >> 2);
      const bf16* gsrc = agsrc_base + (size_t)row * DIN + k0 + (lane & 3) * 8;
      __builtin_amdgcn_global_load_lds((gvoid*)gsrc,
                                       (lvoid*)&Alds[cidx * 512], 16, 0, 0);
    }

    // --- B: W tile 32x128 fp32 -> bf16, transposed into [n][k] ---
    const float* wrow = W + ((size_t)e * DIN + k0 + br) * DOUT + n0;
#pragma unroll
    for (int p = 0; p < 4; ++p) {
      const int nq = bq + p * 8;                    // n-quad 0..31
      const float4 wv = *reinterpret_cast<const float4*>(wrow + nq * 4);
      bf16* bl = &Blds[(nq * 4) * KPAD + br];
      bl[0 * KPAD] = (bf16)wv.x;
      bl[1 * KPAD] = (bf16)wv.y;
      bl[2 * KPAD] = (bf16)wv.z;
      bl[3 * KPAD] = (bf16)wv.w;
    }
    __syncthreads();

    // --- fragments + MFMA ---
    // A frag: lane reads A[m = base + (lane&15)][k = (lane>>4)*8 ..+7]
    // B frag: lane reads B[k = (lane>>4)*8 ..+7][n = base + (lane&15)]
    bf16x8v af[4], bfr[4];
#pragma unroll
    for (int mi = 0; mi < 4; ++mi)
      af[mi] = *reinterpret_cast<const bf16x8v*>(
          &Alds[(warp_m * 64 + mi * 16 + (lane & 15)) * BK + (lane >> 4) * 8]);
#pragma unroll
    for (int ni = 0; ni < 4; ++ni)
      bfr[ni] = *reinterpret_cast<const bf16x8v*>(
          &Blds[(warp_n * 64 + ni * 16 + (lane & 15)) * KPAD + (lane >> 4) * 8]);
#pragma unroll
    for (int mi = 0; mi < 4; ++mi)
#pragma unroll
      for (int ni = 0; ni < 4; ++ni)
        acc[mi][ni] = __builtin_amdgcn_mfma_f32_16x16x32_bf16(
            af[mi], bfr[ni], acc[mi][ni], 0, 0, 0);
  }

  // --- epilogue: + bias, tanh-GELU (jax.nn.gelu approximate=True), fp32 out ---
  // D frag: lane holds D[row = (lane>>4)*4 + r][col = lane&15]
  const float* be = bias + (size_t)e * DOUT;
#pragma unroll
  for (int ni = 0; ni < 4; ++ni) {
    const int col = n0 + warp_n * 64 + ni * 16 + (lane & 15);
    const float bc = be[col];
#pragma unroll
    for (int mi = 0; mi < 4; ++mi) {
#pragma unroll
      for (int rr = 0; rr < 4; ++rr) {
        const int row = t0 + warp_m * 64 + mi * 16 + (lane >> 4) * 4 + rr;
        float v = acc[mi][ni][rr] + bc;
        const float u = 0.7978845608028654f * (v + 0.044715f * v * v * v);
        v = 0.5f * v * (1.0f + tanhf(u));
        out[(size_t)row * DOUT + col] = v;
      }
    }
  }
}

extern "C" void kernel_launch(void* const* d_in, const int* in_sizes, int n_in,
                              void* d_out, int out_size, void* d_ws, size_t ws_size,
                              hipStream_t stream) {
  const float* x     = (const float*)d_in[0];
  // d_in[1] = expert_frequency: balanced by construction (512 each) -> unused
  const float* gamma = (const float*)d_in[2];
  const float* beta  = (const float*)d_in[3];
  const float* W     = (const float*)d_in[4];
  const float* bias  = (const float*)d_in[5];
  float* out = (float*)d_out;
  bf16* xn   = (bf16*)d_ws;    // 8192*1024 bf16 = 16 MiB scratch

  hipLaunchKernelGGL(ln_bf16_kernel, dim3(T_TOK), dim3(256), 0, stream,
                     x, gamma, beta, xn);
  hipLaunchKernelGGL(grouped_gemm_kernel, dim3(DOUT / BN, T_TOK / BM), dim3(256),
                     0, stream, xn, W, bias, out);
}